// Round 1
// baseline (5283.558 us; speedup 1.0000x reference)
//
#include <hip/hip_runtime.h>
#include <math.h>

#define BB 4
#define SS 2048
#define DD 512
#define HH 8
#define HD 64
#define NTOK (BB*SS)
#define EPS 1e-5f

// ---------------- LayerNorm (optional residual) ----------------
// one block (256 thr) per row of D=512; each thread handles 2 elements
__global__ __launch_bounds__(256) void ln_kernel(const float* __restrict__ x,
                                                 const float* __restrict__ res,
                                                 const float* __restrict__ gamma,
                                                 const float* __restrict__ beta,
                                                 float* __restrict__ y) {
    int row = blockIdx.x;
    const float* xr = x + (size_t)row * DD;
    float* yr = y + (size_t)row * DD;
    int t = threadIdx.x;
    float2 v = ((const float2*)xr)[t];
    if (res) {
        float2 r = ((const float2*)(res + (size_t)row * DD))[t];
        v.x += r.x; v.y += r.y;
    }
    float s = v.x + v.y;
    float ss = v.x * v.x + v.y * v.y;
    #pragma unroll
    for (int off = 32; off; off >>= 1) {
        s  += __shfl_down(s,  off);
        ss += __shfl_down(ss, off);
    }
    __shared__ float ws0[4], ws1[4];
    int wid = t >> 6, lane = t & 63;
    if (lane == 0) { ws0[wid] = s; ws1[wid] = ss; }
    __syncthreads();
    __shared__ float mu_s, rstd_s;
    if (t == 0) {
        float S0 = ws0[0] + ws0[1] + ws0[2] + ws0[3];
        float S1 = ws1[0] + ws1[1] + ws1[2] + ws1[3];
        float mu = S0 * (1.0f / DD);
        float var = S1 * (1.0f / DD) - mu * mu;
        mu_s = mu;
        rstd_s = rsqrtf(var + EPS);
    }
    __syncthreads();
    float mu = mu_s, rstd = rstd_s;
    float2 g = ((const float2*)gamma)[t];
    float2 bb = ((const float2*)beta)[t];
    float2 o;
    o.x = (v.x - mu) * rstd * g.x + bb.x;
    o.y = (v.y - mu) * rstd * g.y + bb.y;
    ((float2*)yr)[t] = o;
}

// ---------------- GEMM: C[M,N] = A[M,K] @ W[N,K]^T ----------------
#define BM 64
#define BN 64
#define BK 16
__global__ __launch_bounds__(256) void gemm_xwt(const float* __restrict__ A,
                                                const float* __restrict__ W,
                                                float* __restrict__ C,
                                                int M, int N, int K) {
    __shared__ float As[BK][BM + 1];
    __shared__ float Bs[BK][BN + 1];
    int tid = threadIdx.x;
    int m0 = blockIdx.y * BM;
    int n0 = blockIdx.x * BN;
    int tx = tid & 15, ty = tid >> 4;
    float acc[4][4] = {};
    int lrow = tid >> 2;        // 0..63
    int lk = (tid & 3) * 4;     // 0,4,8,12
    for (int k0 = 0; k0 < K; k0 += BK) {
        float4 av = *(const float4*)(A + (size_t)(m0 + lrow) * K + k0 + lk);
        float4 wv = *(const float4*)(W + (size_t)(n0 + lrow) * K + k0 + lk);
        As[lk + 0][lrow] = av.x; As[lk + 1][lrow] = av.y;
        As[lk + 2][lrow] = av.z; As[lk + 3][lrow] = av.w;
        Bs[lk + 0][lrow] = wv.x; Bs[lk + 1][lrow] = wv.y;
        Bs[lk + 2][lrow] = wv.z; Bs[lk + 3][lrow] = wv.w;
        __syncthreads();
        #pragma unroll
        for (int kk = 0; kk < BK; ++kk) {
            float a[4], b[4];
            #pragma unroll
            for (int i = 0; i < 4; ++i) a[i] = As[kk][ty * 4 + i];
            #pragma unroll
            for (int j = 0; j < 4; ++j) b[j] = Bs[kk][tx * 4 + j];
            #pragma unroll
            for (int i = 0; i < 4; ++i)
                #pragma unroll
                for (int j = 0; j < 4; ++j)
                    acc[i][j] += a[i] * b[j];
        }
        __syncthreads();
    }
    #pragma unroll
    for (int i = 0; i < 4; ++i) {
        int m = m0 + ty * 4 + i;
        #pragma unroll
        for (int j = 0; j < 4; ++j)
            C[(size_t)m * N + n0 + tx * 4 + j] = acc[i][j];
    }
}

// ---------------- Attention ----------------
// scores[i,j] = k_i . q_j   (i = "key" row owned by this block)
// softmax over j; out_i = sum_j p_j v_j
// one block per (b,h,i); 256 threads; online softmax over chunks of 256 j
__global__ __launch_bounds__(256) void attn_kernel(const float* __restrict__ q,
                                                   const float* __restrict__ k,
                                                   const float* __restrict__ v,
                                                   float* __restrict__ out) {
    int idx = blockIdx.x;
    int i = idx & (SS - 1);
    int bh = idx >> 11;          // S = 2048 = 2^11
    int h = bh & (HH - 1);
    int b = bh >> 3;
    int t = threadIdx.x;
    const size_t head_off = (size_t)h * HD;

    __shared__ float4 kb4[16];
    __shared__ float pbuf[256];
    __shared__ float red[4];
    __shared__ float bm_s;
    __shared__ float ocomb[4][64];

    const float* krow = k + ((size_t)(b * SS + i) * DD) + head_off;
    if (t < 16) kb4[t] = ((const float4*)krow)[t];
    __syncthreads();

    float m_run = -INFINITY;
    float l_run = 0.f;
    int g = t >> 6, d = t & 63;
    float o_acc = 0.f;

    for (int j0 = 0; j0 < SS; j0 += 256) {
        // --- score for j = j0 + t ---
        const float* qrow = q + ((size_t)(b * SS + j0 + t) * DD) + head_off;
        float s = 0.f;
        #pragma unroll
        for (int c = 0; c < 16; ++c) {
            float4 qv = ((const float4*)qrow)[c];
            float4 kv = kb4[c];
            s += qv.x * kv.x + qv.y * kv.y + qv.z * kv.z + qv.w * kv.w;
        }
        // --- block max ---
        float mx = s;
        #pragma unroll
        for (int off = 32; off; off >>= 1) mx = fmaxf(mx, __shfl_down(mx, off));
        if ((t & 63) == 0) red[t >> 6] = mx;
        __syncthreads();
        if (t == 0) bm_s = fmaxf(fmaxf(red[0], red[1]), fmaxf(red[2], red[3]));
        __syncthreads();
        float m_new = fmaxf(m_run, bm_s);
        float p = __expf(s - m_new);
        pbuf[t] = p;
        // --- block sum ---
        float ps = p;
        #pragma unroll
        for (int off = 32; off; off >>= 1) ps += __shfl_down(ps, off);
        if ((t & 63) == 0) red[t >> 6] = ps;
        __syncthreads();
        float l_chunk = red[0] + red[1] + red[2] + red[3];
        float scale = __expf(m_run - m_new);
        l_run = l_run * scale + l_chunk;
        m_run = m_new;
        // --- PV: thread (g,d) handles j' in [g*64, g*64+64) ---
        o_acc *= scale;
        const float* vbase = v + ((size_t)(b * SS + j0 + g * 64) * DD) + head_off + d;
        #pragma unroll 4
        for (int tt = 0; tt < 64; ++tt)
            o_acc += pbuf[g * 64 + tt] * vbase[(size_t)tt * DD];
        __syncthreads();   // pbuf / red reused next chunk
    }

    ocomb[g][d] = o_acc;
    __syncthreads();
    if (t < 64) {
        float o = ocomb[0][t] + ocomb[1][t] + ocomb[2][t] + ocomb[3][t];
        out[((size_t)(b * SS + i) * DD) + head_off + t] = o / l_run;
    }
}

extern "C" void kernel_launch(void* const* d_in, const int* in_sizes, int n_in,
                              void* d_out, int out_size, void* d_ws, size_t ws_size,
                              hipStream_t stream) {
    const float* seq_k = (const float*)d_in[0];
    const float* seq_q = (const float*)d_in[1];
    const float* seq_v = (const float*)d_in[2];
    const float* W1    = (const float*)d_in[3];
    const float* W2    = (const float*)d_in[4];
    const float* W3    = (const float*)d_in[5];
    const float* gamma = (const float*)d_in[6];
    const float* beta  = (const float*)d_in[7];
    float* out = (float*)d_out;

    const size_t NELEM = (size_t)NTOK * DD;   // 4194304
    float* ws   = (float*)d_ws;
    float* v_in = ws;
    float* qb   = ws + 1 * NELEM;
    float* kb   = ws + 2 * NELEM;
    float* vb   = ws + 3 * NELEM;
    float* ao   = ws + 4 * NELEM;

    // 1. pre-LN on seq_v
    hipLaunchKernelGGL(ln_kernel, dim3(NTOK), dim3(256), 0, stream,
                       seq_v, nullptr, gamma, beta, v_in);
    // 2. projections
    dim3 ggrid(DD / BN, NTOK / BM);
    hipLaunchKernelGGL(gemm_xwt, ggrid, dim3(256), 0, stream, seq_q, W1, qb, NTOK, DD, DD);
    hipLaunchKernelGGL(gemm_xwt, ggrid, dim3(256), 0, stream, seq_k, W2, kb, NTOK, DD, DD);
    hipLaunchKernelGGL(gemm_xwt, ggrid, dim3(256), 0, stream, v_in,  W3, vb, NTOK, DD, DD);
    // 3. attention
    hipLaunchKernelGGL(attn_kernel, dim3(BB * HH * SS), dim3(256), 0, stream,
                       qb, kb, vb, ao);
    // 4. residual + final LN
    hipLaunchKernelGGL(ln_kernel, dim3(NTOK), dim3(256), 0, stream,
                       ao, v_in, gamma, beta, out);
}

// Round 2
// 493.177 us; speedup vs baseline: 10.7133x; 10.7133x over previous
//
#include <hip/hip_runtime.h>
#include <math.h>

#define BB 4
#define SS 2048
#define DD 512
#define HH 8
#define HD 64
#define NTOK (BB*SS)
#define EPS 1e-5f

typedef _Float16 half8v __attribute__((ext_vector_type(8)));
typedef _Float16 half4v __attribute__((ext_vector_type(4)));
typedef float f32x4 __attribute__((ext_vector_type(4)));

// ---------------- LayerNorm (optional residual) ----------------
__global__ __launch_bounds__(256) void ln_kernel(const float* __restrict__ x,
                                                 const float* __restrict__ res,
                                                 const float* __restrict__ gamma,
                                                 const float* __restrict__ beta,
                                                 float* __restrict__ y) {
    int row = blockIdx.x;
    const float* xr = x + (size_t)row * DD;
    float* yr = y + (size_t)row * DD;
    int t = threadIdx.x;
    float2 v = ((const float2*)xr)[t];
    if (res) {
        float2 r = ((const float2*)(res + (size_t)row * DD))[t];
        v.x += r.x; v.y += r.y;
    }
    float s = v.x + v.y;
    float ss = v.x * v.x + v.y * v.y;
    #pragma unroll
    for (int off = 32; off; off >>= 1) {
        s  += __shfl_down(s,  off);
        ss += __shfl_down(ss, off);
    }
    __shared__ float ws0[4], ws1[4];
    int wid = t >> 6, lane = t & 63;
    if (lane == 0) { ws0[wid] = s; ws1[wid] = ss; }
    __syncthreads();
    __shared__ float mu_s, rstd_s;
    if (t == 0) {
        float S0 = ws0[0] + ws0[1] + ws0[2] + ws0[3];
        float S1 = ws1[0] + ws1[1] + ws1[2] + ws1[3];
        float mu = S0 * (1.0f / DD);
        float var = S1 * (1.0f / DD) - mu * mu;
        mu_s = mu;
        rstd_s = rsqrtf(var + EPS);
    }
    __syncthreads();
    float mu = mu_s, rstd = rstd_s;
    float2 g = ((const float2*)gamma)[t];
    float2 bb = ((const float2*)beta)[t];
    float2 o;
    o.x = (v.x - mu) * rstd * g.x + bb.x;
    o.y = (v.y - mu) * rstd * g.y + bb.y;
    ((float2*)yr)[t] = o;
}

// ---------------- GEMM: Ch[b,h,s,d] (f16) = A[M,K] @ W[N,K]^T ----------------
#define BM 64
#define BN 64
#define BK 16
__global__ __launch_bounds__(256) void gemm_xwt_h(const float* __restrict__ A,
                                                  const float* __restrict__ W,
                                                  _Float16* __restrict__ Ch) {
    __shared__ float As[BK][BM + 1];
    __shared__ float Bs[BK][BN + 1];
    int tid = threadIdx.x;
    int m0 = blockIdx.y * BM;
    int n0 = blockIdx.x * BN;
    int tx = tid & 15, ty = tid >> 4;
    float acc[4][4] = {};
    int lrow = tid >> 2;
    int lk = (tid & 3) * 4;
    for (int k0 = 0; k0 < DD; k0 += BK) {
        float4 av = *(const float4*)(A + (size_t)(m0 + lrow) * DD + k0 + lk);
        float4 wv = *(const float4*)(W + (size_t)(n0 + lrow) * DD + k0 + lk);
        As[lk + 0][lrow] = av.x; As[lk + 1][lrow] = av.y;
        As[lk + 2][lrow] = av.z; As[lk + 3][lrow] = av.w;
        Bs[lk + 0][lrow] = wv.x; Bs[lk + 1][lrow] = wv.y;
        Bs[lk + 2][lrow] = wv.z; Bs[lk + 3][lrow] = wv.w;
        __syncthreads();
        #pragma unroll
        for (int kk = 0; kk < BK; ++kk) {
            float a[4], b[4];
            #pragma unroll
            for (int i = 0; i < 4; ++i) a[i] = As[kk][ty * 4 + i];
            #pragma unroll
            for (int j = 0; j < 4; ++j) b[j] = Bs[kk][tx * 4 + j];
            #pragma unroll
            for (int i = 0; i < 4; ++i)
                #pragma unroll
                for (int j = 0; j < 4; ++j)
                    acc[i][j] += a[i] * b[j];
        }
        __syncthreads();
    }
    // epilogue: write f16, head-split layout [b][h][s][d]; n0 is head-aligned (BN=64=HD)
    int h = n0 >> 6;
    #pragma unroll
    for (int i = 0; i < 4; ++i) {
        int m = m0 + ty * 4 + i;
        int b = m >> 11, s = m & (SS - 1);
        half4v o;
        #pragma unroll
        for (int j = 0; j < 4; ++j) o[j] = (_Float16)acc[i][j];
        *(half4v*)&Ch[(((size_t)(b * HH + h) * SS + s) * HD) + tx * 4] = o;
    }
}

// ---------------- V transpose: vh[b,h,s,d] -> vt[b,h,d,s] ----------------
__global__ __launch_bounds__(256) void transpose_v(const _Float16* __restrict__ vh,
                                                   _Float16* __restrict__ vt) {
    __shared__ __align__(16) _Float16 tile[64 * 72];
    int t = threadIdx.x;
    int s0 = blockIdx.x * 64;
    int bh = blockIdx.y;
    const _Float16* src = vh + ((size_t)bh * SS) * HD;
    _Float16* dst = vt + ((size_t)bh * HD) * SS;
    #pragma unroll
    for (int p = 0; p < 2; ++p) {
        int idx = t + 256 * p;
        int r = idx >> 3, seg = idx & 7;
        *(half8v*)&tile[r * 72 + seg * 8] =
            *(const half8v*)&src[(size_t)(s0 + r) * HD + seg * 8];
    }
    __syncthreads();
    #pragma unroll
    for (int p = 0; p < 2; ++p) {
        int idx = t + 256 * p;
        int d = idx >> 3, seg = idx & 7;
        half8v o;
        #pragma unroll
        for (int e = 0; e < 8; ++e) o[e] = tile[(seg * 8 + e) * 72 + d];
        *(half8v*)&dst[(size_t)d * SS + s0 + seg * 8] = o;
    }
}

// ---------------- Flash attention (quirk: S = K @ Q^T, softmax over q-axis) ----
// block: 128 i-rows (rows of K) for one (b,h); 4 waves x 32 rows; j-tiles of 64
#define BI 128
#define BJ 64
#define LDH 72   // LDS row stride in halves (144 B: 16B-aligned, conflict-tiling)
__global__ __launch_bounds__(256) void attn_mfma(const _Float16* __restrict__ qh,
                                                 const _Float16* __restrict__ kh,
                                                 const _Float16* __restrict__ vt,
                                                 float* __restrict__ out) {
    __shared__ __align__(16) _Float16 Kt[BI * LDH];
    __shared__ __align__(16) _Float16 Qt[BJ * LDH];
    __shared__ __align__(16) _Float16 Vs[HD * LDH];   // rows=d, cols=j
    __shared__ __align__(16) _Float16 Pt[BI * LDH];

    int t = threadIdx.x;
    int w = t >> 6;
    int lane = t & 63;
    int quad = lane >> 4;
    int ln = lane & 15;
    int i0 = blockIdx.x * BI;
    int bh = blockIdx.y;
    int b = bh >> 3, h = bh & 7;

    const _Float16* Kbase = kh + ((size_t)bh * SS) * HD;
    const _Float16* Qbase = qh + ((size_t)bh * SS) * HD;
    const _Float16* Vbase = vt + ((size_t)bh * HD) * SS;

    // stage K tile: 128 rows x 64 halves
    #pragma unroll
    for (int p = 0; p < 4; ++p) {
        int idx = t + 256 * p;
        int r = idx >> 3, seg = idx & 7;
        *(half8v*)&Kt[r * LDH + seg * 8] =
            *(const half8v*)&Kbase[(size_t)(i0 + r) * HD + seg * 8];
    }

    f32x4 oacc[2][4];
    float m_run[2][4], l_run[2][4];
    #pragma unroll
    for (int mi = 0; mi < 2; ++mi)
        #pragma unroll
        for (int x = 0; x < 4; ++x) {
            oacc[mi][x] = (f32x4){0.f, 0.f, 0.f, 0.f};
            m_run[mi][x] = -1e30f;
            l_run[mi][x] = 0.f;
        }

    for (int j0 = 0; j0 < SS; j0 += BJ) {
        // stage Q (64 j-rows x 64 d) and V^T (64 d-rows x 64 j)
        #pragma unroll
        for (int p = 0; p < 2; ++p) {
            int idx = t + 256 * p;
            int r = idx >> 3, seg = idx & 7;
            *(half8v*)&Qt[r * LDH + seg * 8] =
                *(const half8v*)&Qbase[(size_t)(j0 + r) * HD + seg * 8];
            *(half8v*)&Vs[r * LDH + seg * 8] =
                *(const half8v*)&Vbase[(size_t)r * SS + j0 + seg * 8];
        }
        __syncthreads();

        // ---- S = K_tile . Q_tile^T  (M=i 32/wave, N=j 64, K=d 64) ----
        f32x4 sacc[2][4];
        #pragma unroll
        for (int mi = 0; mi < 2; ++mi)
            #pragma unroll
            for (int nj = 0; nj < 4; ++nj)
                sacc[mi][nj] = (f32x4){0.f, 0.f, 0.f, 0.f};
        #pragma unroll
        for (int kk = 0; kk < 2; ++kk) {
            half8v a0 = *(half8v*)&Kt[(w * 32 + ln) * LDH + kk * 32 + quad * 8];
            half8v a1 = *(half8v*)&Kt[(w * 32 + 16 + ln) * LDH + kk * 32 + quad * 8];
            #pragma unroll
            for (int nj = 0; nj < 4; ++nj) {
                half8v bf = *(half8v*)&Qt[(nj * 16 + ln) * LDH + kk * 32 + quad * 8];
                sacc[0][nj] = __builtin_amdgcn_mfma_f32_16x16x32_f16(a0, bf, sacc[0][nj], 0, 0, 0);
                sacc[1][nj] = __builtin_amdgcn_mfma_f32_16x16x32_f16(a1, bf, sacc[1][nj], 0, 0, 0);
            }
        }

        // ---- online softmax over j; C-layout: row=quad*4+reg, col=lane&15 ----
        #pragma unroll
        for (int mi = 0; mi < 2; ++mi) {
            #pragma unroll
            for (int r = 0; r < 4; ++r) {
                float v0 = fmaxf(fmaxf(sacc[mi][0][r], sacc[mi][1][r]),
                                 fmaxf(sacc[mi][2][r], sacc[mi][3][r]));
                v0 = fmaxf(v0, __shfl_xor(v0, 1));
                v0 = fmaxf(v0, __shfl_xor(v0, 2));
                v0 = fmaxf(v0, __shfl_xor(v0, 4));
                v0 = fmaxf(v0, __shfl_xor(v0, 8));
                float mo = m_run[mi][r];
                float mn = fmaxf(mo, v0);
                float alpha = __expf(mo - mn);
                int prow = w * 32 + mi * 16 + quad * 4 + r;
                float psum = 0.f;
                #pragma unroll
                for (int nj = 0; nj < 4; ++nj) {
                    float p = __expf(sacc[mi][nj][r] - mn);
                    psum += p;
                    Pt[prow * LDH + nj * 16 + ln] = (_Float16)p;
                }
                psum += __shfl_xor(psum, 1);
                psum += __shfl_xor(psum, 2);
                psum += __shfl_xor(psum, 4);
                psum += __shfl_xor(psum, 8);
                l_run[mi][r] = l_run[mi][r] * alpha + psum;
                m_run[mi][r] = mn;
                #pragma unroll
                for (int dj = 0; dj < 4; ++dj) oacc[mi][dj][r] *= alpha;
            }
        }
        __syncthreads();

        // ---- O += P . V  (M=i, N=d 64, K=j 64); B needs V^T[d][j] rows ----
        #pragma unroll
        for (int ks = 0; ks < 2; ++ks) {
            half8v a0 = *(half8v*)&Pt[(w * 32 + ln) * LDH + ks * 32 + quad * 8];
            half8v a1 = *(half8v*)&Pt[(w * 32 + 16 + ln) * LDH + ks * 32 + quad * 8];
            #pragma unroll
            for (int dj = 0; dj < 4; ++dj) {
                half8v bf = *(half8v*)&Vs[(dj * 16 + ln) * LDH + ks * 32 + quad * 8];
                oacc[0][dj] = __builtin_amdgcn_mfma_f32_16x16x32_f16(a0, bf, oacc[0][dj], 0, 0, 0);
                oacc[1][dj] = __builtin_amdgcn_mfma_f32_16x16x32_f16(a1, bf, oacc[1][dj], 0, 0, 0);
            }
        }
        __syncthreads();
    }

    // ---- epilogue: O /= l ; write fp32 [b,s,h*64+d] ----
    #pragma unroll
    for (int mi = 0; mi < 2; ++mi)
        #pragma unroll
        for (int r = 0; r < 4; ++r) {
            int i = i0 + w * 32 + mi * 16 + quad * 4 + r;
            float inv = 1.0f / l_run[mi][r];
            #pragma unroll
            for (int dj = 0; dj < 4; ++dj)
                out[((size_t)(b * SS + i)) * DD + h * HD + dj * 16 + ln] =
                    oacc[mi][dj][r] * inv;
        }
}

extern "C" void kernel_launch(void* const* d_in, const int* in_sizes, int n_in,
                              void* d_out, int out_size, void* d_ws, size_t ws_size,
                              hipStream_t stream) {
    const float* seq_k = (const float*)d_in[0];
    const float* seq_q = (const float*)d_in[1];
    const float* seq_v = (const float*)d_in[2];
    const float* W1    = (const float*)d_in[3];
    const float* W2    = (const float*)d_in[4];
    const float* W3    = (const float*)d_in[5];
    const float* gamma = (const float*)d_in[6];
    const float* beta  = (const float*)d_in[7];
    float* out = (float*)d_out;

    const size_t F32B = (size_t)NTOK * DD * 4;   // 16 MB
    const size_t F16B = (size_t)NTOK * DD * 2;   // 8 MB
    char* w8 = (char*)d_ws;
    float*    v_in = (float*)   (w8);
    float*    ao   = (float*)   (w8 + F32B);
    _Float16* qh   = (_Float16*)(w8 + 2 * F32B);
    _Float16* kh   = (_Float16*)(w8 + 2 * F32B + F16B);
    _Float16* vh   = (_Float16*)(w8 + 2 * F32B + 2 * F16B);
    _Float16* vt   = (_Float16*)(w8 + 2 * F32B + 3 * F16B);

    // 1. pre-LN on seq_v
    hipLaunchKernelGGL(ln_kernel, dim3(NTOK), dim3(256), 0, stream,
                       seq_v, nullptr, gamma, beta, v_in);
    // 2. projections -> f16 head-split
    dim3 ggrid(DD / BN, NTOK / BM);
    hipLaunchKernelGGL(gemm_xwt_h, ggrid, dim3(256), 0, stream, seq_q, W1, qh);
    hipLaunchKernelGGL(gemm_xwt_h, ggrid, dim3(256), 0, stream, seq_k, W2, kh);
    hipLaunchKernelGGL(gemm_xwt_h, ggrid, dim3(256), 0, stream, v_in,  W3, vh);
    // 3. V transpose for PV B-operand
    hipLaunchKernelGGL(transpose_v, dim3(SS / 64, BB * HH), dim3(256), 0, stream, vh, vt);
    // 4. flash attention (MFMA f16)
    hipLaunchKernelGGL(attn_mfma, dim3(SS / BI, BB * HH), dim3(256), 0, stream,
                       qh, kh, vt, ao);
    // 5. residual + final LN
    hipLaunchKernelGGL(ln_kernel, dim3(NTOK), dim3(256), 0, stream,
                       ao, v_in, gamma, beta, out);
}

// Round 3
// 228.499 us; speedup vs baseline: 23.1229x; 2.1583x over previous
//
#include <hip/hip_runtime.h>
#include <math.h>

#define BB 4
#define SS 2048
#define DD 512
#define HH 8
#define HD 64
#define NTOK (BB*SS)
#define EPS 1e-5f

typedef _Float16 half8v __attribute__((ext_vector_type(8)));
typedef _Float16 half4v __attribute__((ext_vector_type(4)));
typedef _Float16 half2v __attribute__((ext_vector_type(2)));
typedef float f32x4 __attribute__((ext_vector_type(4)));

__device__ __forceinline__ void gload_lds16(const void* g, void* l) {
    __builtin_amdgcn_global_load_lds(
        (const __attribute__((address_space(1))) unsigned int*)g,
        (__attribute__((address_space(3))) unsigned int*)l, 16, 0, 0);
}

// ---------------- LayerNorm (optional residual, optional f16 copy) ----------
__global__ __launch_bounds__(256) void ln_kernel(const float* __restrict__ x,
                                                 const float* __restrict__ res,
                                                 const float* __restrict__ gamma,
                                                 const float* __restrict__ beta,
                                                 float* __restrict__ y,
                                                 _Float16* __restrict__ y16) {
    int row = blockIdx.x;
    const float* xr = x + (size_t)row * DD;
    int t = threadIdx.x;
    float2 v = ((const float2*)xr)[t];
    if (res) {
        float2 r = ((const float2*)(res + (size_t)row * DD))[t];
        v.x += r.x; v.y += r.y;
    }
    float s = v.x + v.y;
    float ss = v.x * v.x + v.y * v.y;
    #pragma unroll
    for (int off = 32; off; off >>= 1) {
        s  += __shfl_down(s,  off);
        ss += __shfl_down(ss, off);
    }
    __shared__ float ws0[4], ws1[4];
    int wid = t >> 6, lane = t & 63;
    if (lane == 0) { ws0[wid] = s; ws1[wid] = ss; }
    __syncthreads();
    __shared__ float mu_s, rstd_s;
    if (t == 0) {
        float S0 = ws0[0] + ws0[1] + ws0[2] + ws0[3];
        float S1 = ws1[0] + ws1[1] + ws1[2] + ws1[3];
        float mu = S0 * (1.0f / DD);
        float var = S1 * (1.0f / DD) - mu * mu;
        mu_s = mu;
        rstd_s = rsqrtf(var + EPS);
    }
    __syncthreads();
    float mu = mu_s, rstd = rstd_s;
    float2 g = ((const float2*)gamma)[t];
    float2 bb = ((const float2*)beta)[t];
    float2 o;
    o.x = (v.x - mu) * rstd * g.x + bb.x;
    o.y = (v.y - mu) * rstd * g.y + bb.y;
    if (y)   ((float2*)(y + (size_t)row * DD))[t] = o;
    if (y16) {
        half2v ho; ho[0] = (_Float16)o.x; ho[1] = (_Float16)o.y;
        *(half2v*)&y16[(size_t)row * DD + 2 * t] = ho;
    }
}

// ---------------- fp32 -> f16 cast ----------------
__global__ __launch_bounds__(256) void cast_f2h(const float* __restrict__ src,
                                                _Float16* __restrict__ dst) {
    size_t i = ((size_t)blockIdx.x * 256 + threadIdx.x) * 4;
    float4 v = *(const float4*)(src + i);
    half4v o;
    o[0] = (_Float16)v.x; o[1] = (_Float16)v.y;
    o[2] = (_Float16)v.z; o[3] = (_Float16)v.w;
    *(half4v*)(dst + i) = o;
}

// ---------------- MFMA GEMM: C = A[M,K] @ W[N,K]^T, f16 in, f16 head-split out
#define GBM 128
#define GBN 128
#define GBK 64
__global__ __launch_bounds__(256) void gemm_mfma(const _Float16* __restrict__ Aall,
                                                 const _Float16* __restrict__ Wall,
                                                 _Float16* __restrict__ Call) {
    __shared__ __align__(16) _Float16 As[GBM * GBK];
    __shared__ __align__(16) _Float16 Ws[GBN * GBK];
    int z = blockIdx.z;
    const _Float16* A = Aall + (size_t)z * NTOK * DD;
    const _Float16* W = Wall + (size_t)z * DD * DD;
    _Float16* C = Call + (size_t)z * NTOK * DD;
    int t = threadIdx.x, w = t >> 6, lane = t & 63, q = lane >> 4, ln = lane & 15;
    int lrow = lane >> 3, lseg = lane & 7;
    int m0 = blockIdx.y * GBM, n0 = blockIdx.x * GBN;
    int wm = w & 1, wn = w >> 1;
    f32x4 acc[4][4];
    #pragma unroll
    for (int mt = 0; mt < 4; ++mt)
        #pragma unroll
        for (int nt = 0; nt < 4; ++nt)
            acc[mt][nt] = (f32x4){0.f, 0.f, 0.f, 0.f};

    int gs = lseg ^ lrow;   // XOR-swizzled source chunk
    for (int k0 = 0; k0 < DD; k0 += GBK) {
        #pragma unroll
        for (int p = 0; p < 4; ++p) {
            int r = w * 32 + p * 8 + lrow;
            gload_lds16(A + (size_t)(m0 + r) * DD + k0 + gs * 8,
                        As + (size_t)(w * 32 + p * 8) * GBK);
            gload_lds16(W + (size_t)(n0 + r) * DD + k0 + gs * 8,
                        Ws + (size_t)(w * 32 + p * 8) * GBK);
        }
        __syncthreads();
        #pragma unroll
        for (int kk = 0; kk < 2; ++kk) {
            int ch = ((4 * kk + q) ^ (ln & 7)) * 8;
            half8v af[4], wf[4];
            #pragma unroll
            for (int mt = 0; mt < 4; ++mt)
                af[mt] = *(half8v*)&As[(wm * 64 + mt * 16 + ln) * GBK + ch];
            #pragma unroll
            for (int nt = 0; nt < 4; ++nt)
                wf[nt] = *(half8v*)&Ws[(wn * 64 + nt * 16 + ln) * GBK + ch];
            #pragma unroll
            for (int mt = 0; mt < 4; ++mt)
                #pragma unroll
                for (int nt = 0; nt < 4; ++nt)
                    acc[mt][nt] = __builtin_amdgcn_mfma_f32_16x16x32_f16(
                        af[mt], wf[nt], acc[mt][nt], 0, 0, 0);
        }
        __syncthreads();
    }
    // epilogue: head-split [b][h][s][d] f16
    #pragma unroll
    for (int mt = 0; mt < 4; ++mt) {
        int mbase = m0 + wm * 64 + mt * 16 + q * 4;
        #pragma unroll
        for (int nt = 0; nt < 4; ++nt) {
            int n = n0 + wn * 64 + nt * 16 + ln;
            int h = n >> 6, d = n & 63;
            #pragma unroll
            for (int r = 0; r < 4; ++r) {
                int m = mbase + r;
                int b = m >> 11, s = m & (SS - 1);
                C[(((size_t)(b * HH + h) * SS + s) * HD) + d] = (_Float16)acc[mt][nt][r];
            }
        }
    }
}

// ---------------- V transpose: vh[b,h,s,d] -> vt[b,h,d,s] ----------------
__global__ __launch_bounds__(256) void transpose_v(const _Float16* __restrict__ vh,
                                                   _Float16* __restrict__ vt) {
    __shared__ __align__(16) _Float16 tile[64 * 72];
    int t = threadIdx.x;
    int s0 = blockIdx.x * 64;
    int bh = blockIdx.y;
    const _Float16* src = vh + ((size_t)bh * SS) * HD;
    _Float16* dst = vt + ((size_t)bh * HD) * SS;
    #pragma unroll
    for (int p = 0; p < 2; ++p) {
        int idx = t + 256 * p;
        int r = idx >> 3, seg = idx & 7;
        *(half8v*)&tile[r * 72 + seg * 8] =
            *(const half8v*)&src[(size_t)(s0 + r) * HD + seg * 8];
    }
    __syncthreads();
    #pragma unroll
    for (int p = 0; p < 2; ++p) {
        int idx = t + 256 * p;
        int d = idx >> 3, seg = idx & 7;
        half8v o;
        #pragma unroll
        for (int e = 0; e < 8; ++e) o[e] = tile[(seg * 8 + e) * 72 + d];
        *(half8v*)&dst[(size_t)d * SS + s0 + seg * 8] = o;
    }
}

// ---------------- Flash attention, S^T orientation ----------------
// scores S[i][j] = k_i . q_j, softmax over j. We compute S^T[j][i] = Q.K^T so
// the softmax axis is the MFMA row axis (in-register). K frags live in VGPRs;
// P goes through wave-private LDS (no barrier); O^T = V^T . P^T.
#define AI 128
#define AJ 64
#define PLD 72
__global__ __launch_bounds__(256) void attn_mfma(const _Float16* __restrict__ qh,
                                                 const _Float16* __restrict__ kh,
                                                 const _Float16* __restrict__ vt,
                                                 float* __restrict__ out) {
    __shared__ __align__(16) _Float16 Qt[AJ * HD];      // rows j, 64x64, XOR-swizzled
    __shared__ __align__(16) _Float16 Vs[HD * AJ];      // rows d, 64x64, XOR-swizzled
    __shared__ __align__(16) _Float16 Ps[8 * 16 * PLD]; // [w*2+nt][ln][j], wave-private
    int t = threadIdx.x, w = t >> 6, lane = t & 63, q = lane >> 4, ln = lane & 15;
    int lrow = lane >> 3, lseg = lane & 7;
    int i0 = blockIdx.x * AI;
    int bh = blockIdx.y, b = bh >> 3, h = bh & 7;
    const _Float16* Kb = kh + (size_t)bh * SS * HD;
    const _Float16* Qb = qh + (size_t)bh * SS * HD;
    const _Float16* Vb = vt + (size_t)bh * HD * SS;

    // K fragments (B-operand): rows i0 + w*32 + nt*16 + ln, held for all j
    half8v kf[2][2];
    #pragma unroll
    for (int nt = 0; nt < 2; ++nt)
        #pragma unroll
        for (int kk = 0; kk < 2; ++kk)
            kf[nt][kk] = *(const half8v*)&Kb[(size_t)(i0 + w * 32 + nt * 16 + ln) * HD
                                             + kk * 32 + q * 8];

    f32x4 oacc[4][2];
    float m_run[2], l_run[2];
    #pragma unroll
    for (int nt = 0; nt < 2; ++nt) {
        m_run[nt] = -3.0e38f;
        l_run[nt] = 0.f;
        #pragma unroll
        for (int mtd = 0; mtd < 4; ++mtd) oacc[mtd][nt] = (f32x4){0.f, 0.f, 0.f, 0.f};
    }

    int gs = lseg ^ lrow;
    for (int j0 = 0; j0 < SS; j0 += AJ) {
        // stage Q (64 j-rows x 64 d) and V^T (64 d-rows x 64 j), async + swizzle
        #pragma unroll
        for (int p = 0; p < 2; ++p) {
            int r = w * 16 + p * 8 + lrow;
            gload_lds16(Qb + (size_t)(j0 + r) * HD + gs * 8,
                        Qt + (size_t)(w * 16 + p * 8) * HD);
            gload_lds16(Vb + (size_t)r * SS + j0 + gs * 8,
                        Vs + (size_t)(w * 16 + p * 8) * AJ);
        }
        __syncthreads();

        // ---- S^T = Q . K^T : M=j (64), N=i (32/wave), K=d (64) ----
        f32x4 sacc[4][2];
        #pragma unroll
        for (int mt = 0; mt < 4; ++mt)
            #pragma unroll
            for (int nt = 0; nt < 2; ++nt)
                sacc[mt][nt] = (f32x4){0.f, 0.f, 0.f, 0.f};
        #pragma unroll
        for (int kk = 0; kk < 2; ++kk) {
            int ch = ((4 * kk + q) ^ (ln & 7)) * 8;
            half8v qf[4];
            #pragma unroll
            for (int mt = 0; mt < 4; ++mt)
                qf[mt] = *(half8v*)&Qt[(mt * 16 + ln) * HD + ch];
            #pragma unroll
            for (int mt = 0; mt < 4; ++mt)
                #pragma unroll
                for (int nt = 0; nt < 2; ++nt)
                    sacc[mt][nt] = __builtin_amdgcn_mfma_f32_16x16x32_f16(
                        qf[mt], kf[nt][kk], sacc[mt][nt], 0, 0, 0);
        }

        // ---- online softmax over j (rows): in-register + 2 shuffles ----
        #pragma unroll
        for (int nt = 0; nt < 2; ++nt) {
            float mx = -3.0e38f;
            #pragma unroll
            for (int mt = 0; mt < 4; ++mt)
                #pragma unroll
                for (int r = 0; r < 4; ++r) mx = fmaxf(mx, sacc[mt][nt][r]);
            mx = fmaxf(mx, __shfl_xor(mx, 16));
            mx = fmaxf(mx, __shfl_xor(mx, 32));
            float mo = m_run[nt];
            float mn = fmaxf(mo, mx);
            float al = __expf(mo - mn);
            m_run[nt] = mn;
            float ps = 0.f;
            #pragma unroll
            for (int mt = 0; mt < 4; ++mt) {
                half4v pv;
                #pragma unroll
                for (int r = 0; r < 4; ++r) {
                    float p = __expf(sacc[mt][nt][r] - mn);
                    ps += p;
                    pv[r] = (_Float16)p;
                }
                *(half4v*)&Ps[((size_t)(w * 2 + nt) * 16 + ln) * PLD + mt * 16 + q * 4] = pv;
            }
            ps += __shfl_xor(ps, 16);
            ps += __shfl_xor(ps, 32);
            l_run[nt] = l_run[nt] * al + ps;
            #pragma unroll
            for (int mtd = 0; mtd < 4; ++mtd) oacc[mtd][nt] *= al;
        }

        // ---- O^T += V^T . P^T : M=d (64), N=i (32/wave), K=j (64) ----
        #pragma unroll
        for (int ks = 0; ks < 2; ++ks) {
            int ch = ((4 * ks + q) ^ (ln & 7)) * 8;
            half8v vf[4], pf[2];
            #pragma unroll
            for (int mtd = 0; mtd < 4; ++mtd)
                vf[mtd] = *(half8v*)&Vs[(mtd * 16 + ln) * AJ + ch];
            #pragma unroll
            for (int nt = 0; nt < 2; ++nt)
                pf[nt] = *(half8v*)&Ps[((size_t)(w * 2 + nt) * 16 + ln) * PLD + ks * 32 + q * 8];
            #pragma unroll
            for (int mtd = 0; mtd < 4; ++mtd)
                #pragma unroll
                for (int nt = 0; nt < 2; ++nt)
                    oacc[mtd][nt] = __builtin_amdgcn_mfma_f32_16x16x32_f16(
                        vf[mtd], pf[nt], oacc[mtd][nt], 0, 0, 0);
        }
        __syncthreads();   // Qt/Vs reused next iter
    }

    // ---- epilogue: O[i][d] = O^T[d][i] / l ; float4 stores ----
    #pragma unroll
    for (int nt = 0; nt < 2; ++nt) {
        float inv = 1.0f / l_run[nt];
        int i = i0 + w * 32 + nt * 16 + ln;
        #pragma unroll
        for (int mtd = 0; mtd < 4; ++mtd) {
            float4 o;
            o.x = oacc[mtd][nt][0] * inv;
            o.y = oacc[mtd][nt][1] * inv;
            o.z = oacc[mtd][nt][2] * inv;
            o.w = oacc[mtd][nt][3] * inv;
            *(float4*)&out[(size_t)(b * SS + i) * DD + h * HD + mtd * 16 + q * 4] = o;
        }
    }
}

extern "C" void kernel_launch(void* const* d_in, const int* in_sizes, int n_in,
                              void* d_out, int out_size, void* d_ws, size_t ws_size,
                              hipStream_t stream) {
    const float* seq_k = (const float*)d_in[0];
    const float* seq_q = (const float*)d_in[1];
    const float* seq_v = (const float*)d_in[2];
    const float* W1    = (const float*)d_in[3];
    const float* W2    = (const float*)d_in[4];
    const float* W3    = (const float*)d_in[5];
    const float* gamma = (const float*)d_in[6];
    const float* beta  = (const float*)d_in[7];
    float* out = (float*)d_out;

    const size_t NE = (size_t)NTOK * DD;           // 4194304
    const size_t MB = 1024 * 1024;
    char* w8 = (char*)d_ws;
    float*    v_in = (float*)w8;                    // [0,16) MiB
    _Float16* a16  = (_Float16*)(w8 + 16 * MB);     // q16,k16,v16: [16,40)
    _Float16* w16  = (_Float16*)(w8 + 40 * MB);     // [40,41.5)
    _Float16* proj = (_Float16*)(w8 + 48 * MB);     // qh,kh,vh: [48,72)
    _Float16* vt   = (_Float16*)(w8 + 72 * MB);     // [72,80)
    float*    ao   = (float*)(w8 + 16 * MB);        // aliases q16/k16 (done by then)

    _Float16* q16 = a16;
    _Float16* k16 = a16 + NE;
    _Float16* v16 = a16 + 2 * NE;
    _Float16* qh  = proj;
    _Float16* kh  = proj + NE;
    _Float16* vh  = proj + 2 * NE;

    // 1. pre-LN on seq_v -> fp32 (residual) + f16 (GEMM A)
    hipLaunchKernelGGL(ln_kernel, dim3(NTOK), dim3(256), 0, stream,
                       seq_v, (const float*)nullptr, gamma, beta, v_in, v16);
    // 2. casts
    hipLaunchKernelGGL(cast_f2h, dim3(NE / 1024), dim3(256), 0, stream, seq_q, q16);
    hipLaunchKernelGGL(cast_f2h, dim3(NE / 1024), dim3(256), 0, stream, seq_k, k16);
    hipLaunchKernelGGL(cast_f2h, dim3((DD * DD) / 1024), dim3(256), 0, stream, W1, w16);
    hipLaunchKernelGGL(cast_f2h, dim3((DD * DD) / 1024), dim3(256), 0, stream, W2, w16 + (size_t)DD * DD);
    hipLaunchKernelGGL(cast_f2h, dim3((DD * DD) / 1024), dim3(256), 0, stream, W3, w16 + 2 * (size_t)DD * DD);
    // 3. fused projections (z: q,k,v)
    hipLaunchKernelGGL(gemm_mfma, dim3(DD / GBN, NTOK / GBM, 3), dim3(256), 0, stream,
                       a16, w16, proj);
    // 4. V transpose
    hipLaunchKernelGGL(transpose_v, dim3(SS / 64, BB * HH), dim3(256), 0, stream, vh, vt);
    // 5. flash attention
    hipLaunchKernelGGL(attn_mfma, dim3(SS / AI, BB * HH), dim3(256), 0, stream,
                       qh, kh, vt, ao);
    // 6. residual + final LN
    hipLaunchKernelGGL(ln_kernel, dim3(NTOK), dim3(256), 0, stream,
                       ao, v_in, gamma, beta, out, (_Float16*)nullptr);
}